// Round 15
// baseline (342.741 us; speedup 1.0000x reference)
//
#include <hip/hip_runtime.h>
#include <hip/hip_bf16.h>

typedef float  f32x4 __attribute__((ext_vector_type(4)));
typedef short  s16x8 __attribute__((ext_vector_type(8)));

#define MEMH   256        // mem_dim
#define MSGD   512        // msg_dim
#define G3     768        // 3*H
#define W_IH_ELEMS (G3*MSGD)        // 393216
#define W_HH_ELEMS (G3*MEMH)        // 196608
#define W_TOT_ELEMS (W_IH_ELEMS + W_HH_ELEMS)  // 589824
#define W_BYTES    ((size_t)W_TOT_ELEMS * 2)   // 1179648

#define BM     64         // rows per GRU block
#define NTHR   1024       // 16 waves
// LDS layout (fused kernel):
#define WB_OFF   0        // W k-slice buffer: 48 tiles x 1 KB = 49152 B
#define AM_OFF   49152    // A_msg: 64x512 bf16, pitch 1024 B -> 65536 B
#define AH_OFF   114688   // A_h:   64x256 bf16, pitch 512 B  -> 32768 B
#define PART_OFF 147456   // part[64][16][2] f32 -> 8192 B
#define STAT_OFF 155648   // stat[64][2] f32 -> 512 B
#define LDS_BYTES 156160

typedef const __attribute__((address_space(1))) void* gas_p;
typedef __attribute__((address_space(3)))       void* las_p;

static __device__ __forceinline__ short f2bf(float x) {
    __hip_bfloat16 b = __float2bfloat16(x);
    return __builtin_bit_cast(short, b);
}
static __device__ __forceinline__ float bf2f(short s) {
    unsigned int u = ((unsigned int)(unsigned short)s) << 16;
    return __builtin_bit_cast(float, u);
}
static __device__ __forceinline__ s16x8 cvt8(f32x4 a, f32x4 b) {
    s16x8 s;
    s[0]=f2bf(a[0]); s[1]=f2bf(a[1]); s[2]=f2bf(a[2]); s[3]=f2bf(a[3]);
    s[4]=f2bf(b[0]); s[5]=f2bf(b[1]); s[6]=f2bf(b[2]); s[7]=f2bf(b[3]);
    return s;
}
static __device__ __forceinline__ float sigf(float x) {
    return 1.f / (1.f + __expf(-x));
}
static __device__ __forceinline__ float tanh_fast(float x) {
    float e = __expf(-2.f * fabsf(x));
    float t = (1.f - e) / (1.f + e);
    return copysignf(t, x);
}
static __device__ __forceinline__ f32x4 ntload4(const float* p) {
    return __builtin_nontemporal_load((const f32x4*)p);
}
static __device__ __forceinline__ void ntstore4(float* p, f32x4 v) {
    __builtin_nontemporal_store(v, (f32x4*)p);
}

// ------------------------------------------------- full copy kernel (fallback)
__global__ void smu_copy_kernel(const float* __restrict__ mem,
                                const float* __restrict__ lu,
                                float* __restrict__ out_mem,
                                float* __restrict__ out_lu,
                                long n_mem4, long n_lu4) {
    long i = (long)blockIdx.x * blockDim.x + threadIdx.x;
    long stride = (long)gridDim.x * blockDim.x;
    long total = n_mem4 + n_lu4;
    for (; i < total; i += stride) {
        if (i < n_mem4) ntstore4(out_mem + i * 4, ntload4(mem + i * 4));
        else {
            long j = (i - n_mem4) * 4;
            ntstore4(out_lu + j, ntload4(lu + j));
        }
    }
}

// --------------------------------------------------- weight fp32->bf16 K-MAJOR packed layout
// ih: frag (k in [0,16), t in [0,48)) at elem off (k*48+t)*512 -> one K-slice
// (fixed k, all 48 tiles) is 48 KB CONTIGUOUS. Within frag elem idx = l*8+e
// <- source row t*16+(l&15), col k*32+(l>>4)*8+e.
// hh: frag (k in [0,8), t in [0,48)) at W_IH_ELEMS + (k*48+t)*512, same inner map.
__global__ void smu_cvtw_kernel(const float* __restrict__ wih,
                                const float* __restrict__ whh,
                                short* __restrict__ o) {
    int i = blockIdx.x * blockDim.x + threadIdx.x;
    if (i >= W_TOT_ELEMS) return;
    if (i < W_IH_ELEMS) {
        int f = i >> 9, r = i & 511, l = r >> 3, e = r & 7;
        int k = f / 48, t = f - k * 48;
        int row = t * 16 + (l & 15), col = k * 32 + (l >> 4) * 8 + e;
        o[i] = f2bf(wih[row * MSGD + col]);
    } else {
        int j = i - W_IH_ELEMS;
        int f = j >> 9, r = j & 511, l = r >> 3, e = r & 7;
        int k = f / 48, t = f - k * 48;
        int row = t * 16 + (l & 15), col = k * 32 + (l >> 4) * 8 + e;
        o[i] = f2bf(whh[row * MEMH + col]);
    }
}

// --------------------------------------------------- bitmap clear + set
__global__ void smu_clear_kernel(unsigned* __restrict__ p, int n) {
    int i = blockIdx.x * blockDim.x + threadIdx.x;
    if (i < n) p[i] = 0u;
}
__global__ void smu_bits_kernel(const int* __restrict__ ids,
                                unsigned* __restrict__ bm, int n) {
    int i = blockIdx.x * blockDim.x + threadIdx.x;
    if (i < n) {
        int id = ids[i];
        atomicOr(&bm[id >> 5], 1u << (id & 31));
    }
}

// --------------------------------------------------------------- fused kernel
// grid = 2*1024. Even blocks: GRU+LN (BM=64). Odd blocks: bitmap-skip copy.
// GRU k-loop uses COOPERATIVE WEIGHT STAGING (canonical §5 pattern, new this
// round): per k-step the block bulk-DMAs the 48 KB k-major weight slice into
// LDS via global_load_lds dwordx4 (wave w stages tiles 3w..3w+2, linear dest),
// stage of slice k+1 issued right after the all-read barrier so its flight
// overlaps compute(k). Replaces per-wave direct L2 fragment loads (the
// serialized-latency pattern that pinned the GRU phase at ~165 us).
__global__ __launch_bounds__(NTHR, 1)
void smu_fused_kernel(const int*   __restrict__ ids,
                      const float* __restrict__ msg,
                      const float* __restrict__ ts,
                      const float* __restrict__ memory,
                      const float* __restrict__ lu,
                      const float* __restrict__ b_ih,
                      const float* __restrict__ b_hh,
                      const float* __restrict__ gamma,
                      const float* __restrict__ beta,
                      const short* __restrict__ wsw,
                      const unsigned* __restrict__ bm,
                      float* __restrict__ out_mem,
                      float* __restrict__ out_lu,
                      long n_nodes) {
    __shared__ __align__(16) unsigned char lds[LDS_BYTES];
    const int tid = threadIdx.x;
    const int bid = blockIdx.x;

    if (bid & 1) {
        // ================= COPY role (round-7 verbatim) =================
        const long nblk   = gridDim.x >> 1;
        const long cid    = bid >> 1;
        const long nu     = n_nodes * (MEMH / 4);           // 16B units
        const long stride = nblk * NTHR;
        const long i0     = cid * NTHR + tid;

        for (long i = i0; i < nu; i += stride * 4) {
            long  u0 = i, u1 = i + stride, u2 = i + stride * 2, u3 = i + stride * 3;
            f32x4 v0, v1, v2, v3;
            bool  f0 = false, f1 = false, f2 = false, f3 = false;
            {
                long r0 = u0 >> 6;
                f0 = !((bm[r0 >> 5] >> (r0 & 31)) & 1u);
                if (f0) v0 = ntload4(memory + u0 * 4);
            }
            if (u1 < nu) {
                long r1 = u1 >> 6;
                f1 = !((bm[r1 >> 5] >> (r1 & 31)) & 1u);
                if (f1) v1 = ntload4(memory + u1 * 4);
            }
            if (u2 < nu) {
                long r2 = u2 >> 6;
                f2 = !((bm[r2 >> 5] >> (r2 & 31)) & 1u);
                if (f2) v2 = ntload4(memory + u2 * 4);
            }
            if (u3 < nu) {
                long r3 = u3 >> 6;
                f3 = !((bm[r3 >> 5] >> (r3 & 31)) & 1u);
                if (f3) v3 = ntload4(memory + u3 * 4);
            }
            if (f0) ntstore4(out_mem + u0 * 4, v0);
            if (f1) ntstore4(out_mem + u1 * 4, v1);
            if (f2) ntstore4(out_mem + u2 * 4, v2);
            if (f3) ntstore4(out_mem + u3 * 4, v3);
        }
        for (long i = i0; i < n_nodes; i += stride) {
            if (!((bm[i >> 5] >> (i & 31)) & 1u)) {
                float v = __builtin_nontemporal_load(lu + i);
                __builtin_nontemporal_store(v, out_lu + i);
            }
        }
        return;
    }

    // ================= GRU role =================
    const long base = (long)(bid >> 1) * BM;

    // ---- stage A_msg: 64x512 f32 -> bf16 (4096 8-elem units, 4/thread)
    {
        const float* src = msg + base * MSGD;
        #pragma unroll
        for (int it = 0; it < 4; ++it) {
            int u = tid + NTHR * it;         // 0..4095
            int row = u >> 6;                // 64 units per row
            f32x4 a = ntload4(src + u * 8);
            f32x4 b = ntload4(src + u * 8 + 4);
            int byte = AM_OFF + ((u * 16) ^ ((row & 7) << 4));
            *(s16x8*)(lds + byte) = cvt8(a, b);
        }
        // ---- stage A_h (gather): 64x256 (2048 units, 2/thread)
        #pragma unroll
        for (int it = 0; it < 2; ++it) {
            int u = tid + NTHR * it;         // 0..2047
            int row = u >> 5;                // 32 units per row
            int c8  = u & 31;
            int id  = ids[base + row];
            const float* hs = memory + (size_t)id * MEMH + c8 * 8;
            f32x4 a = ntload4(hs);
            f32x4 b = ntload4(hs + 4);
            int byte = AH_OFF + ((u * 16) ^ ((row & 7) << 4));
            *(s16x8*)(lds + byte) = cvt8(a, b);
        }
    }

    const int lane = tid & 63;
    const int w    = tid >> 6;              // 0..15
    const int lr   = lane & 15;
    const int lq   = lane >> 4;             // 0..3
    const int lk8  = lq * 8;
    const int sw   = (lr & 7) << 4;
    const short* Wi = wsw;                  // k-major ih: slice k at (k*48)<<9
    const short* Wh = wsw + W_IH_ELEMS;     // k-major hh

    // per-wave staging: tiles 3w, 3w+1, 3w+2 of the 48 KB slice
    const int tile0 = 3 * w;

    // stage ih slice 0 (issued before the staging barrier; drained with it)
    #pragma unroll
    for (int g = 0; g < 3; ++g)
        __builtin_amdgcn_global_load_lds(
            (gas_p)(const void*)(Wi + ((size_t)(0 * 48 + tile0 + g) << 9) + lane * 8),
            (las_p)(void*)(lds + WB_OFF + (tile0 + g) * 1024), 16, 0, 0);
    __syncthreads();   // A staging + W slice 0 all complete

    f32x4 acc[4][3] = {};   // [m][0]=r-sum  [1]=z-sum  [2]=gi_n
    f32x4 accn[4]   = {};   // gh_n

    // ---- GEMM 1: gi += msg @ W_ih^T  (K=512, 16 k-slices)
    #pragma unroll
    for (int k = 0; k < 16; ++k) {
        // read this wave's 3 B fragments from the staged slice
        s16x8 b0 = *(const s16x8*)(lds + WB_OFF + (w)      * 1024 + lane * 16);
        s16x8 b1 = *(const s16x8*)(lds + WB_OFF + (w + 16) * 1024 + lane * 16);
        s16x8 b2 = *(const s16x8*)(lds + WB_OFF + (w + 32) * 1024 + lane * 16);
        __syncthreads();   // all waves have read slice k (own lgkm drained)
        // issue next slice's DMAs; flight overlaps compute below
        if (k < 15) {
            #pragma unroll
            for (int g = 0; g < 3; ++g)
                __builtin_amdgcn_global_load_lds(
                    (gas_p)(const void*)(Wi + ((size_t)((k + 1) * 48 + tile0 + g) << 9) + lane * 8),
                    (las_p)(void*)(lds + WB_OFF + (tile0 + g) * 1024), 16, 0, 0);
        } else {
            #pragma unroll
            for (int g = 0; g < 3; ++g)
                __builtin_amdgcn_global_load_lds(
                    (gas_p)(const void*)(Wh + ((size_t)(0 * 48 + tile0 + g) << 9) + lane * 8),
                    (las_p)(void*)(lds + WB_OFF + (tile0 + g) * 1024), 16, 0, 0);
        }
        const int cb = (k * 32 + lk8) * 2;
        #pragma unroll
        for (int m = 0; m < 4; ++m) {
            s16x8 a = *(const s16x8*)(lds + AM_OFF + (((m*16 + lr) * 1024 + cb) ^ sw));
            acc[m][0] = __builtin_amdgcn_mfma_f32_16x16x32_bf16(a, b0, acc[m][0], 0, 0, 0);
            acc[m][1] = __builtin_amdgcn_mfma_f32_16x16x32_bf16(a, b1, acc[m][1], 0, 0, 0);
            acc[m][2] = __builtin_amdgcn_mfma_f32_16x16x32_bf16(a, b2, acc[m][2], 0, 0, 0);
        }
        asm volatile("s_waitcnt vmcnt(0)" ::: "memory");
        __syncthreads();   // next slice landed everywhere
    }

    // ---- GEMM 2: h @ W_hh^T  (K=256, 8 k-slices; slice 0 already staged)
    #pragma unroll
    for (int k = 0; k < 8; ++k) {
        s16x8 b0 = *(const s16x8*)(lds + WB_OFF + (w)      * 1024 + lane * 16);
        s16x8 b1 = *(const s16x8*)(lds + WB_OFF + (w + 16) * 1024 + lane * 16);
        s16x8 b2 = *(const s16x8*)(lds + WB_OFF + (w + 32) * 1024 + lane * 16);
        __syncthreads();
        if (k < 7) {
            #pragma unroll
            for (int g = 0; g < 3; ++g)
                __builtin_amdgcn_global_load_lds(
                    (gas_p)(const void*)(Wh + ((size_t)((k + 1) * 48 + tile0 + g) << 9) + lane * 8),
                    (las_p)(void*)(lds + WB_OFF + (tile0 + g) * 1024), 16, 0, 0);
        }
        const int cb = (k * 32 + lk8) * 2;
        #pragma unroll
        for (int m = 0; m < 4; ++m) {
            s16x8 a = *(const s16x8*)(lds + AH_OFF + (((m*16 + lr) * 512 + cb) ^ sw));
            acc[m][0] = __builtin_amdgcn_mfma_f32_16x16x32_bf16(a, b0, acc[m][0], 0, 0, 0);
            acc[m][1] = __builtin_amdgcn_mfma_f32_16x16x32_bf16(a, b1, acc[m][1], 0, 0, 0);
            accn[m]   = __builtin_amdgcn_mfma_f32_16x16x32_bf16(a, b2, accn[m],   0, 0, 0);
        }
        if (k < 7) {
            asm volatile("s_waitcnt vmcnt(0)" ::: "memory");
            __syncthreads();
        }
    }

    // ---- gate epilogue IN REGISTERS (A_h LDS intact). Lane column j.
    const int j = w * 16 + lr;               // 0..255
    f32x4 o_[4];
    {
        const float br = b_ih[j]       + b_hh[j];
        const float bz = b_ih[256 + j] + b_hh[256 + j];
        const float bihn = b_ih[512 + j], bhhn = b_hh[512 + j];
        #pragma unroll
        for (int m = 0; m < 4; ++m) {
            #pragma unroll
            for (int q = 0; q < 4; ++q) {
                int row = m * 16 + lq * 4 + q;
                float r = sigf(acc[m][0][q] + br);
                float z = sigf(acc[m][1][q] + bz);
                float n = tanh_fast(acc[m][2][q] + bihn + r * (accn[m][q] + bhhn));
                float hv = bf2f(*(const short*)(lds + AH_OFF + ((row * 512 + j * 2) ^ ((row & 7) << 4))));
                o_[m][q] = (1.f - z) * n + z * hv;
            }
        }
    }

    // ---- per-wave LN partials: sum over this wave's 16 cols per row
    {
        float* part = (float*)(lds + PART_OFF);
        #pragma unroll
        for (int m = 0; m < 4; ++m) {
            #pragma unroll
            for (int q = 0; q < 4; ++q) {
                float v = o_[m][q];
                float s1 = v, s2 = v * v;
                #pragma unroll
                for (int mk = 1; mk < 16; mk <<= 1) {
                    s1 += __shfl_xor(s1, mk);
                    s2 += __shfl_xor(s2, mk);
                }
                if (lr == 0) {
                    int row = m * 16 + lq * 4 + q;
                    part[(row * 16 + w) * 2]     = s1;
                    part[(row * 16 + w) * 2 + 1] = s2;
                }
            }
        }
    }
    __syncthreads();

    // ---- stage-2: wave w reduces rows 4w..4w+3 (lane group lq -> one row)
    {
        const float* part = (const float*)(lds + PART_OFF);
        int row = w * 4 + lq;
        float s1 = part[(row * 16 + lr) * 2];
        float s2 = part[(row * 16 + lr) * 2 + 1];
        #pragma unroll
        for (int mk = 1; mk < 16; mk <<= 1) {
            s1 += __shfl_xor(s1, mk);
            s2 += __shfl_xor(s2, mk);
        }
        if (lr == 0) {
            float mu  = s1 * (1.f / 256.f);
            float var = fmaxf(s2 * (1.f / 256.f) - mu * mu, 0.f);
            float* st = (float*)(lds + STAT_OFF);
            st[row * 2]     = mu;
            st[row * 2 + 1] = rsqrtf(var + 1e-5f);
        }
    }
    __syncthreads();

    // ---- normalize + scatter
    {
        const float* st = (const float*)(lds + STAT_OFF);
        const float ga = gamma[j], be = beta[j];
        #pragma unroll
        for (int m = 0; m < 4; ++m) {
            #pragma unroll
            for (int q = 0; q < 4; ++q) {
                int row = m * 16 + lq * 4 + q;
                float mu  = st[row * 2];
                float inv = st[row * 2 + 1];
                int id = ids[base + row];
                float y = (o_[m][q] - mu) * inv * ga + be;
                __builtin_nontemporal_store(y, out_mem + (size_t)id * MEMH + j);
            }
        }
        if (w == 0) {
            int id = ids[base + lane];
            __builtin_nontemporal_store(ts[base + lane], out_lu + id);
        }
    }
}

// --------------------------------------------------------------- GRU-only fallback (no workspace)
__global__ __launch_bounds__(512, 4)
void smu_gru_fb_kernel(const int*   __restrict__ ids,
                       const float* __restrict__ msg,
                       const float* __restrict__ ts,
                       const float* __restrict__ memory,
                       const float* __restrict__ W_ih,
                       const float* __restrict__ W_hh,
                       const float* __restrict__ b_ih,
                       const float* __restrict__ b_hh,
                       const float* __restrict__ gamma,
                       const float* __restrict__ beta,
                       float* __restrict__ out_mem,
                       float* __restrict__ out_lu) {
    __shared__ __align__(16) unsigned char lds[51200];
    const int tid = threadIdx.x;
    const long base = (long)blockIdx.x * 32;

    {
        const float* src = msg + base * MSGD;
        #pragma unroll
        for (int it = 0; it < 4; ++it) {
            int u = tid + 512 * it;
            int row = u >> 6;
            f32x4 a = ntload4(src + u * 8);
            f32x4 b = ntload4(src + u * 8 + 4);
            int byte = ((u * 16) ^ ((row & 7) << 4));
            *(s16x8*)(lds + byte) = cvt8(a, b);
        }
        #pragma unroll
        for (int it = 0; it < 2; ++it) {
            int u = tid + 512 * it;
            int row = u >> 5;
            int c8  = u & 31;
            int id  = ids[base + row];
            const float* hs = memory + (size_t)id * MEMH + c8 * 8;
            f32x4 a = ntload4(hs);
            f32x4 b = ntload4(hs + 4);
            int byte = 32768 + ((u * 16) ^ ((row & 7) << 4));
            *(s16x8*)(lds + byte) = cvt8(a, b);
        }
    }
    __syncthreads();

    const int lane = tid & 63;
    const int w    = tid >> 6;
    const int lr   = lane & 15;
    const int lq   = lane >> 4;
    const int lk8  = lq * 8;
    const int sw   = (lr & 7) << 4;

    auto loadb = [&](const float* Wf, int t, int k, int ldk) {
        int row = t * 16 + lr;
        int col = k * 32 + lk8;
        f32x4 x = *(const f32x4*)(Wf + (size_t)row * ldk + col);
        f32x4 y = *(const f32x4*)(Wf + (size_t)row * ldk + col + 4);
        return cvt8(x, y);
    };

    f32x4 rz[2][2][2] = {};
    f32x4 gin[2][2]   = {};
    f32x4 ghn[2][2]   = {};

    for (int k = 0; k < 16; ++k) {
        const int cb = (k * 32 + lk8) * 2;
        #pragma unroll
        for (int m = 0; m < 2; ++m) {
            s16x8 a = *(const s16x8*)(lds + (((m*16 + lr) * 1024 + cb) ^ sw));
            #pragma unroll
            for (int ci = 0; ci < 2; ++ci) {
                s16x8 b0 = loadb(W_ih, w + 8*ci + 0,  k, MSGD);
                s16x8 b1 = loadb(W_ih, w + 8*ci + 16, k, MSGD);
                s16x8 b2 = loadb(W_ih, w + 8*ci + 32, k, MSGD);
                rz[m][ci][0] = __builtin_amdgcn_mfma_f32_16x16x32_bf16(a, b0, rz[m][ci][0], 0, 0, 0);
                rz[m][ci][1] = __builtin_amdgcn_mfma_f32_16x16x32_bf16(a, b1, rz[m][ci][1], 0, 0, 0);
                gin[m][ci]   = __builtin_amdgcn_mfma_f32_16x16x32_bf16(a, b2, gin[m][ci],   0, 0, 0);
            }
        }
    }
    for (int k = 0; k < 8; ++k) {
        const int cb = (k * 32 + lk8) * 2;
        #pragma unroll
        for (int m = 0; m < 2; ++m) {
            s16x8 a = *(const s16x8*)(lds + 32768 + (((m*16 + lr) * 512 + cb) ^ sw));
            #pragma unroll
            for (int ci = 0; ci < 2; ++ci) {
                s16x8 b0 = loadb(W_hh, w + 8*ci + 0,  k, MEMH);
                s16x8 b1 = loadb(W_hh, w + 8*ci + 16, k, MEMH);
                s16x8 b2 = loadb(W_hh, w + 8*ci + 32, k, MEMH);
                rz[m][ci][0] = __builtin_amdgcn_mfma_f32_16x16x32_bf16(a, b0, rz[m][ci][0], 0, 0, 0);
                rz[m][ci][1] = __builtin_amdgcn_mfma_f32_16x16x32_bf16(a, b1, rz[m][ci][1], 0, 0, 0);
                ghn[m][ci]   = __builtin_amdgcn_mfma_f32_16x16x32_bf16(a, b2, ghn[m][ci],   0, 0, 0);
            }
        }
    }

    f32x4 o_[2][2];
    #pragma unroll
    for (int ci = 0; ci < 2; ++ci) {
        const int j = (w + 8*ci) * 16 + lr;
        const float br = b_ih[j]       + b_hh[j];
        const float bz = b_ih[256 + j] + b_hh[256 + j];
        const float bihn = b_ih[512 + j], bhhn = b_hh[512 + j];
        #pragma unroll
        for (int m = 0; m < 2; ++m) {
            #pragma unroll
            for (int q = 0; q < 4; ++q) {
                int row = m * 16 + lq * 4 + q;
                float r = sigf(rz[m][ci][0][q] + br);
                float z = sigf(rz[m][ci][1][q] + bz);
                float n = tanh_fast(gin[m][ci][q] + bihn + r * (ghn[m][ci][q] + bhhn));
                float hv = bf2f(*(const short*)(lds + 32768 + ((row * 512 + j * 2) ^ ((row & 7) << 4))));
                o_[m][ci][q] = (1.f - z) * n + z * hv;
            }
        }
    }

    float* part = (float*)(lds + 49152);
    #pragma unroll
    for (int m = 0; m < 2; ++m)
        #pragma unroll
        for (int q = 0; q < 4; ++q) {
            float v0 = o_[m][0][q], v1 = o_[m][1][q];
            float s1 = v0 + v1, s2 = v0*v0 + v1*v1;
            #pragma unroll
            for (int mk = 1; mk < 16; mk <<= 1) {
                s1 += __shfl_xor(s1, mk);
                s2 += __shfl_xor(s2, mk);
            }
            if (lr == 0) {
                int row = m * 16 + lq * 4 + q;
                part[(row * 8 + w) * 2]     = s1;
                part[(row * 8 + w) * 2 + 1] = s2;
            }
        }
    __syncthreads();

    #pragma unroll
    for (int ci = 0; ci < 2; ++ci) {
        const int j = (w + 8*ci) * 16 + lr;
        const float ga = gamma[j], be = beta[j];
        #pragma unroll
        for (int m = 0; m < 2; ++m)
            #pragma unroll
            for (int q = 0; q < 4; ++q) {
                int row = m * 16 + lq * 4 + q;
                float s1 = 0.f, s2 = 0.f;
                #pragma unroll
                for (int i = 0; i < 8; ++i) {
                    s1 += part[(row * 8 + i) * 2];
                    s2 += part[(row * 8 + i) * 2 + 1];
                }
                float mu  = s1 * (1.f / 256.f);
                float var = fmaxf(s2 * (1.f / 256.f) - mu * mu, 0.f);
                float inv = rsqrtf(var + 1e-5f);
                int id = ids[base + row];
                float y = (o_[m][ci][q] - mu) * inv * ga + be;
                __builtin_nontemporal_store(y, out_mem + (size_t)id * MEMH + j);
            }
    }
    if (w == 0 && lane < 32) {
        int id = ids[base + lane];
        __builtin_nontemporal_store(ts[base + lane], out_lu + id);
    }
}

// ------------------------------------------------------------------- launcher
extern "C" void kernel_launch(void* const* d_in, const int* in_sizes, int n_in,
                              void* d_out, int out_size, void* d_ws, size_t ws_size,
                              hipStream_t stream) {
    (void)n_in; (void)out_size;
    const int*   ids = (const int*)  d_in[0];
    const float* msg = (const float*)d_in[1];
    const float* ts  = (const float*)d_in[2];
    const float* mem = (const float*)d_in[3];
    const float* lu  = (const float*)d_in[4];
    const float* Wih = (const float*)d_in[5];
    const float* Whh = (const float*)d_in[6];
    const float* bih = (const float*)d_in[7];
    const float* bhh = (const float*)d_in[8];
    const float* gam = (const float*)d_in[9];
    const float* bet = (const float*)d_in[10];

    const int  n_upd   = in_sizes[0];                 // 65536
    const long n_nodes = (long)in_sizes[3] / MEMH;    // 500000

    float* out_mem = (float*)d_out;
    float* out_lu  = out_mem + (size_t)n_nodes * MEMH;

    const int    bm_words     = (int)((n_nodes + 31) / 32) + 4;   // padded
    const size_t bm_bytes_pad = (size_t)bm_words * 4;
    const bool ws_ok = (d_ws != nullptr) && (ws_size >= W_BYTES + bm_bytes_pad);

    short*    wsw = (short*)d_ws;
    unsigned* bm  = (unsigned*)((char*)d_ws + W_BYTES);

    const int grid = n_upd / BM;   // 65536/64 = 1024

    if (ws_ok) {
        smu_cvtw_kernel<<<(W_TOT_ELEMS + 255) / 256, 256, 0, stream>>>(Wih, Whh, wsw);
        smu_clear_kernel<<<(bm_words + 255) / 256, 256, 0, stream>>>(bm, bm_words);
        smu_bits_kernel<<<(n_upd + 255) / 256, 256, 0, stream>>>(ids, bm, n_upd);
        // single fused dispatch: even blocks GRU (staged weights), odd copy
        smu_fused_kernel<<<2 * grid, NTHR, 0, stream>>>(
            ids, msg, ts, mem, lu, bih, bhh, gam, bet,
            wsw, bm, out_mem, out_lu, n_nodes);
    } else {
        // fallback: full copy first, then GRU scatter overwrites updated rows
        long n_mem4 = n_nodes * (MEMH / 4);
        long n_lu4  = n_nodes / 4;
        smu_copy_kernel<<<2048, 256, 0, stream>>>(mem, lu, out_mem, out_lu, n_mem4, n_lu4);
        smu_gru_fb_kernel<<<n_upd / 32, 512, 0, stream>>>(
            ids, msg, ts, mem, Wih, Whh, bih, bhh, gam, bet, out_mem, out_lu);
    }
}